// Round 2
// baseline (136.603 us; speedup 1.0000x reference)
//
#include <hip/hip_runtime.h>

#define B_ 16
#define C_ 12
#define H_ 384
#define W_ 384
#define LK 96
#define W4 (W_ / 4)          // 96 float4-groups per row
#define TR 8                 // H-rows per block tile
#define TPB 256
#define GPT 3                // groups per thread: 8*96/256
#define NBLK (B_ * (H_ / TR))  // 768 blocks = 3 per CU exactly
#define NTOT ((double)(B_ * C_ * H_ * W_))

__device__ __forceinline__ float mask_w(float v) {
    // Sequential threshold masking collapses to 3 compares (1.0, 2.0 < T2,
    // so they are overwritten by 5.0 on the third pass). Verified absmax=0.
    const float T2 = (133.0f - 33.44f) / 47.54f;
    const float T3 = (181.0f - 33.44f) / 47.54f;
    const float T4 = (255.0f - 33.44f) / 47.54f;
    return v < T2 ? 5.0f : (v < T3 ? 10.0f : (v < T4 ? 30.0f : v));
}

__global__ __launch_bounds__(TPB, 4) void loss_main(
    const float* __restrict__ y_pre, const float* __restrict__ y_true,
    const float* __restrict__ x_l, const float* __restrict__ wlk,
    double* __restrict__ partial)
{
    __shared__ float lw[C_][4][LK];   // 18432 B: the 4 w_LK rows this tile needs

    const int b  = blockIdx.x / (H_ / TR);
    const int m  = blockIdx.x % (H_ / TR);
    const int h0 = m * TR;

    // --- stage w_LK rows 2m-1 .. 2m+2 (clamped) for all 12 channels ---
    const float* base = wlk + (size_t)b * C_ * LK * LK;
    int R[4];
    #pragma unroll
    for (int i = 0; i < 4; ++i) R[i] = min(max(2 * m - 1 + i, 0), LK - 1);
    for (int i = threadIdx.x; i < C_ * 4 * (LK / 4); i += TPB) {
        const int c  = i / (4 * (LK / 4));
        const int rm = i % (4 * (LK / 4));
        const int rl = rm / (LK / 4);
        const int c4 = rm % (LK / 4);
        const float4 v = *(const float4*)(base + (size_t)c * LK * LK + R[rl] * LK + c4 * 4);
        *(float4*)(&lw[c][rl][c4 * 4]) = v;
    }
    __syncthreads();

    float acc = 0.f;
    for (int gi = 0; gi < GPT; ++gi) {
        const int G  = threadIdx.x + gi * TPB;   // group within tile, row-major
        const int hl = G / W4;
        const int j  = G % W4;
        const int h  = h0 + hl;

        // vertical lerp: frac cycles .625,.875,.125,.375; local top row (hl+2)/4
        const float fh = 0.125f + 0.25f * (float)((hl + 2) & 3);
        const int k0   = (hl + 2) >> 2;
        const int jm1 = max(j - 1, 0), jp1 = min(j + 1, LK - 1);

        const size_t pix = (size_t)h * W_ + (size_t)j * 4;
        const float4 x4 = *(const float4*)(x_l + (size_t)b * H_ * W_ + pix);
        const float xv[4] = {x4.x, x4.y, x4.z, x4.w};
        const size_t ybase = (size_t)b * C_ * H_ * W_ + pix;

        float s[4] = {0.f, 0.f, 0.f, 0.f};   // excl cumsum |y_true_c - x|
        float t[4] = {0.f, 0.f, 0.f, 0.f};   // excl cumsum bilinear(w_LK_c)
        #pragma unroll
        for (int c = 0; c < C_; ++c) {
            const float4 yt4 = *(const float4*)(y_true + ybase + (size_t)c * H_ * W_);
            const float4 yp4 = *(const float4*)(y_pre  + ybase + (size_t)c * H_ * W_);
            const float c0 = lw[c][k0][jm1],     c1 = lw[c][k0][j],     c2 = lw[c][k0][jp1];
            const float d0 = lw[c][k0 + 1][jm1], d1 = lw[c][k0 + 1][j], d2 = lw[c][k0 + 1][jp1];
            const float e0 = c0 + fh * (d0 - c0);
            const float e1 = c1 + fh * (d1 - c1);
            const float e2 = c2 + fh * (d2 - c2);
            float bil[4];
            bil[0] = 0.375f * e0 + 0.625f * e1;
            bil[1] = 0.125f * e0 + 0.875f * e1;
            bil[2] = 0.875f * e1 + 0.125f * e2;
            bil[3] = 0.625f * e1 + 0.375f * e2;

            const float yt[4] = {yt4.x, yt4.y, yt4.z, yt4.w};
            const float yp[4] = {yp4.x, yp4.y, yp4.z, yp4.w};
            #pragma unroll
            for (int r = 0; r < 4; ++r) {
                const float wt = mask_w(yt[r]);
                acc += (wt + s[r] + t[r]) * fabsf(yp[r] - yt[r]);
                s[r] += fabsf(yt[r] - xv[r]);
                t[r] += bil[r];
            }
        }
    }

    // --- block reduction (double) ---
    double v = (double)acc;
    #pragma unroll
    for (int off = 32; off > 0; off >>= 1) v += __shfl_down(v, off, 64);
    __shared__ double lds[TPB / 64];
    const int lane = threadIdx.x & 63, wid = threadIdx.x >> 6;
    if (lane == 0) lds[wid] = v;
    __syncthreads();
    if (threadIdx.x == 0)
        partial[blockIdx.x] = lds[0] + lds[1] + lds[2] + lds[3];
}

__global__ __launch_bounds__(256) void loss_final(
    const double* __restrict__ partial, float* __restrict__ out)
{
    double v = 0.0;
    for (int i = threadIdx.x; i < NBLK; i += 256) v += partial[i];
    #pragma unroll
    for (int off = 32; off > 0; off >>= 1) v += __shfl_down(v, off, 64);
    __shared__ double lds[4];
    const int lane = threadIdx.x & 63, wid = threadIdx.x >> 6;
    if (lane == 0) lds[wid] = v;
    __syncthreads();
    if (threadIdx.x == 0)
        out[0] = (float)((lds[0] + lds[1] + lds[2] + lds[3]) / NTOT);
}

extern "C" void kernel_launch(void* const* d_in, const int* in_sizes, int n_in,
                              void* d_out, int out_size, void* d_ws, size_t ws_size,
                              hipStream_t stream) {
    const float* y_pre  = (const float*)d_in[0];
    const float* y_true = (const float*)d_in[1];
    const float* x_l    = (const float*)d_in[2];
    const float* wlk    = (const float*)d_in[3];
    double* partial = (double*)d_ws;   // NBLK*8 = 6144 bytes

    loss_main<<<NBLK, TPB, 0, stream>>>(y_pre, y_true, x_l, wlk, partial);
    loss_final<<<1, 256, 0, stream>>>(partial, (float*)d_out);
}